// Round 19
// baseline (66.504 us; speedup 1.0000x reference)
//
#include <hip/hip_runtime.h>
#include <math.h>
#include <stdint.h>

#define B_ 4
#define T_ 64000
#define H_ 96
#define NCH 1000
#define TT_ 64
#define TWO_PI_D 6.283185307179586

typedef float2 cplx;
__device__ __forceinline__ cplx cadd(cplx a, cplx b){ return make_float2(a.x+b.x, a.y+b.y); }
__device__ __forceinline__ cplx csub(cplx a, cplx b){ return make_float2(a.x-b.x, a.y-b.y); }
__device__ __forceinline__ cplx cmul(cplx a, cplx b){ return make_float2(a.x*b.x - a.y*b.y, a.x*b.y + a.y*b.x); }

// ---------------- static scratch ----------------
__device__ float  g_dpf[B_*T_];
__device__ unsigned char g_hcnt[B_*T_];
__device__ float  g_signal[B_*T_];
__device__ float  g_shaped[B_*T_];
__device__ float  g_Kcomb[B_][132];
__device__ float2 g_W1[2*512*125];
__device__ float2 g_Z[2*125*512];
__device__ double g_chunksum[B_*NCH];
__device__ double g_stats[B_*2];
__device__ double g_part[B_*NCH*2];

// ---------------- fast f64 transcendentals ----------------
__device__ __forceinline__ double fsin64(double x){
  double z = x * 0.63661977236758138243;
  double fn = floor(z + 0.5);
  int k = (int)fn;
  const double p1 = 1.57079632673412561417e+00;
  const double p2 = 6.07710050650619224932e-11;
  double r = x - fn*p1;
  r = r - fn*p2;
  double s = r*r;
  double ps = 1.58969099521155010221e-10;
  ps = ps*s - 2.50507602534068634195e-08;
  ps = ps*s + 2.75573137070700676789e-06;
  ps = ps*s - 1.98412698298579493134e-04;
  ps = ps*s + 8.33333333332248946124e-03;
  ps = ps*s - 1.66666666666666324348e-01;
  double sr = r + r*s*ps;
  double pc = -1.13596475577881948265e-11;
  pc = pc*s + 2.08757232129817482790e-09;
  pc = pc*s - 2.75573143513906633035e-07;
  pc = pc*s + 2.48015872894767294178e-05;
  pc = pc*s - 1.38888888888741095749e-03;
  pc = pc*s + 4.16666666666666019037e-02;
  double cr = 1.0 - 0.5*s + s*s*pc;
  int m = k & 3;
  return (m==0) ? sr : (m==1) ? cr : (m==2) ? -sr : -cr;
}

__device__ __forceinline__ double fexp_small(double x){
  double p = 1.9841269841269841e-04;
  p = p*x + 1.3888888888888889e-03;
  p = p*x + 8.3333333333333332e-03;
  p = p*x + 4.1666666666666664e-02;
  p = p*x + 1.6666666666666666e-01;
  p = p*x + 0.5;
  p = p*x + 1.0;
  p = p*x + 1.0;
  return p;
}

// ---------------- threefry (partitionable, out0^out1) ----------------
__device__ __forceinline__ uint32_t rotl32(uint32_t x, int r){ return (x<<r)|(x>>(32-r)); }

__device__ __forceinline__ uint32_t threefry_bits(uint32_t i){
  uint32_t x0 = 0u, x1 = i;
  const uint32_t ks0 = 0u, ks1 = 42u, ks2 = 0u ^ 42u ^ 0x1BD11BDAu;
  x0 += ks0; x1 += ks1;
  #define TFR(r) { x0 += x1; x1 = rotl32(x1, r); x1 ^= x0; }
  TFR(13) TFR(15) TFR(26) TFR(6)   x0 += ks1; x1 += ks2 + 1u;
  TFR(17) TFR(29) TFR(16) TFR(24)  x0 += ks2; x1 += ks0 + 2u;
  TFR(13) TFR(15) TFR(26) TFR(6)   x0 += ks0; x1 += ks1 + 3u;
  TFR(17) TFR(29) TFR(16) TFR(24)  x0 += ks1; x1 += ks2 + 4u;
  TFR(13) TFR(15) TFR(26) TFR(6)   x0 += ks2; x1 += ks0 + 5u;
  #undef TFR
  return x0 ^ x1;
}

__device__ __forceinline__ float bits_to_normal(uint32_t bits){
  uint32_t mbits = (bits >> 9) | 0x3F800000u;
  float f = __uint_as_float(mbits) - 1.0f;
  const float lo = -0.99999994f;
  float x = f * 2.0f + lo;
  x = fmaxf(lo, x);
  float w = -log1pf(-x*x);
  float p;
  if (w < 5.0f){
    w -= 2.5f;
    p = 2.81022636e-08f;
    p = fmaf(p, w, 3.43273939e-07f);
    p = fmaf(p, w, -3.5233877e-06f);
    p = fmaf(p, w, -4.39150654e-06f);
    p = fmaf(p, w, 0.00021858087f);
    p = fmaf(p, w, -0.00125372503f);
    p = fmaf(p, w, -0.00417768164f);
    p = fmaf(p, w, 0.246640727f);
    p = fmaf(p, w, 1.50140941f);
  } else {
    w = sqrtf(w) - 3.0f;
    p = -0.000200214257f;
    p = fmaf(p, w, 0.000100950558f);
    p = fmaf(p, w, 0.00134934322f);
    p = fmaf(p, w, -0.00367342844f);
    p = fmaf(p, w, 0.00573950773f);
    p = fmaf(p, w, -0.0076224613f);
    p = fmaf(p, w, 0.00943887047f);
    p = fmaf(p, w, 1.00167406f);
    p = fmaf(p, w, 2.83297682f);
  }
  return 1.4142135623730951f * (p * x);
}

__constant__ int KSZc[8] = {129,91,65,45,33,23,17,11};

// ---------------- phase: increments + hcnt + chunksums (+ per-batch Kcomb in c==0) ----------------
__global__ __launch_bounds__(256) void k_phase(const float* __restrict__ bss,
                                               const float* __restrict__ f0,
                                               const float* __restrict__ vr,
                                               const float* __restrict__ vd){
  int b = blockIdx.x / 250, c = blockIdx.x % 250;
  int t0 = c*256, tid = threadIdx.x;
  if (c == 0){
    __shared__ float wn[8];
    {
      int i = tid >> 5, l32 = tid & 31;
      int ksz = KSZc[i];
      float sig = (float)ksz / 6.0f;
      float inv2s2 = 1.0f/(2.0f*sig*sig);
      int ctr = ksz>>1;
      float s = 0.f;
      for (int j = l32; j < ksz; j += 32){
        float d = (float)(j - ctr);
        s += expf(-d*d*inv2s2);
      }
      #pragma unroll
      for (int o=1;o<32;o<<=1) s += __shfl_xor(s, o);
      if (l32 == 0) wn[i] = bss[((size_t)b*T_ + T_/2)*8 + i] / s;
    }
    __syncthreads();
    if (tid < 129){
      int tau = tid - 64;
      float acc = 0.f;
      #pragma unroll
      for (int i=0;i<8;i++){
        int ksz = KSZc[i]; int hw = ksz>>1;
        if (tau >= -hw && tau <= hw){
          float sig = (float)ksz/6.0f;
          float inv2s2 = 1.0f/(2.0f*sig*sig);
          acc += expf(-(float)(tau*tau)*inv2s2) * wn[i];
        }
      }
      g_Kcomb[b][tid] = acc;
    }
  }
  int t = t0 + tid;
  int idx = b*T_ + t;
  double tt = (double)t * 2.2675736961451248e-05;      // 1/44100
  double argd = TWO_PI_D * (double)vr[idx] * tt;
  double argr = argd - TWO_PI_D * floor(argd * 0.15915494309189535);
  float svf = __sinf((float)argr);
  double lm = (double)vd[idx] * 0.057762265046662105;  // ln2/12
  double vm = fexp_small((double)svf * lm);
  double f0s = (double)f0[idx];
  double f0v = (f0s > 0.0) ? f0s * vm : f0s;
  int cnt;
  if (f0v <= 0.0) cnt = 96;
  else {
    int n = (int)(22050.0f / (float)f0v);
    if (!((double)n * f0v < 22050.0)) n--;
    if ((double)(n+1) * f0v < 22050.0) n++;
    double dlo = 22050.0 - (double)n * f0v;
    double dhi = (double)(n+1) * f0v - 22050.0;
    if (dlo < 0.01 || dhi < 0.01){
      double sv_d = fsin64(argd);
      double vm_d = fexp_small(sv_d * lm);
      double f0x = f0s * vm_d;
      int n2 = (int)(22050.0f / (float)f0x);
      if (!((double)n2 * f0x < 22050.0)) n2--;
      if ((double)(n2+1) * f0x < 22050.0) n2++;
      n = n2;
      f0v = f0x;
    }
    cnt = (n < 0) ? 0 : ((n > 96) ? 96 : n);
  }
  g_hcnt[idx] = (unsigned char)cnt;
  double v = f0v * 1.4247585730565955e-04;             // 2*pi/44100
  g_dpf[idx] = (float)v;
  int lane = tid & 63, wid = tid >> 6;
  for (int o=1;o<64;o<<=1) v += __shfl_down(v, o);
  if (lane == 0) g_chunksum[b*NCH + c*4 + wid] = v;
}

// ---------------- fused: harmonic synth + breath, COALESCED LDS-staged amps ----------------
__global__ __launch_bounds__(256) void k_sigbreath(const float* __restrict__ amps,
                                                   const float* __restrict__ goq,
                                                   const float* __restrict__ iph,
                                                   float* __restrict__ out_final){
  __shared__ __align__(16) float As[TT_*100];   // stride-100 pad: bank-conflict-free reads
  __shared__ float ph[TT_];
  __shared__ float ns[192];
  __shared__ float kl[132];
  __shared__ float shb[TT_];
  int b = blockIdx.x / NCH, c = blockIdx.x % NCH;
  int t0 = c*TT_;
  int tid = threadIdx.x;
  // ===== coalesced staging: consecutive tid -> consecutive float4 (1KB/wave-instr),
  // 6 independent loads in flight; LDS writes land before the barrier =====
  const float4* ag = (const float4*)(amps + ((size_t)b*T_ + t0)*H_);
  #pragma unroll
  for (int u=0;u<6;u++){
    int i4 = tid + u*256;                      // 1536 float4 total
    int row = i4 / 24, col4 = i4 - row*24;
    float4 v = ag[i4];
    *((float4*)&As[row*100 + col4*4]) = v;
  }
  // ---- overlap phase: scan / noise / kl ----
  if (tid < 64){
    double s = 0.0;
    for (int ch = tid; ch < c; ch += 64) s += g_chunksum[b*NCH + ch];
    for (int o=1;o<64;o<<=1) s += __shfl_xor(s, o);
    double base = s + (double)iph[b];
    int idq = b*T_ + t0 + tid;
    double v = (double)g_dpf[idq];
    for (int o=1;o<64;o<<=1){ double u = __shfl_up(v, o); if (tid >= o) v += u; }
    ph[tid] = (float)fmod(base + v, TWO_PI_D);
    if (c == NCH-1 && tid == 63) out_final[b] = (float)fmod(base + v, TWO_PI_D);
  }
  {
    int k = (tid < 64) ? tid + 128 : tid - 64;
    int t = t0 - 64 + k;
    float nv = 0.f;
    if (t >= 0 && t < T_) nv = bits_to_normal(threefry_bits((uint32_t)(b*T_ + t)));
    if (k < 192) ns[k] = nv;
  }
  if (tid >= 192){
    for (int k = tid - 192; k < 129; k += 64) kl[k] = g_Kcomb[b][k];
  }
  __syncthreads();
  int tl = tid >> 2, part = tid & 3;
  // breath conv: 4 lanes per output
  {
    float accb = 0.f;
    for (int j = part; j < 129; j += 4) accb = fmaf(ns[tl + j], kl[j], accb);
    accb += __shfl_xor(accb, 1);
    accb += __shfl_xor(accb, 2);
    if (part == 0) shb[tl] = accb;
  }
  // harmonic synth from LDS
  int idx = b*T_ + t0 + tl;
  float r = ph[tl];
  int hc = (int)g_hcnt[idx];
  float oq = goq[idx];
  float k1 = 3.14159265358979f / oq;
  float k2 = 3.14159265358979f / (1.0f - oq);
  float offA = 3.14159265358979f;
  float offB = -oq * k2;
  float r0 = r * 0.15915494309189535f;
  int hbase = part*24;
  float sum = 0.f;
  const float4* Ar = (const float4*)&As[tl*100 + part*24];
  #pragma unroll
  for (int j4=0;j4<6;j4++){
    float4 a4 = Ar[j4];
    float av0[4] = {a4.x, a4.y, a4.z, a4.w};
    #pragma unroll
    for (int e=0;e<4;e++){
      int h = hbase + j4*4 + e;
      float amp = (h < hc) ? av0[e] : 0.0f;
      float nn = (float)(h+1);
      float fr = nn * r0;
      fr = fr - floorf(fr);
      bool ris = fr < oq;
      float kk  = ris ? k1 : k2;
      float off = ris ? offA : offB;
      float cv = __cosf(fmaf(fr, kk, off));
      sum = fmaf(cv, amp, sum);
    }
  }
  sum += __shfl_xor(sum, 1);
  sum += __shfl_xor(sum, 2);
  if (part == 0) g_signal[idx] = 0.5f * sum;
  // stats partial + shaped write
  __syncthreads();
  if (tid < 64){
    float sv = shb[tid];
    g_shaped[b*T_ + t0 + tid] = sv;
    double xx = (double)sv;
    double s1 = xx, s2 = xx*xx;
    for (int o=1;o<64;o<<=1){ s1 += __shfl_down(s1,o); s2 += __shfl_down(s2,o); }
    if (tid == 0){
      g_part[(b*NCH+c)*2]   = s1;
      g_part[(b*NCH+c)*2+1] = s2;
    }
  }
}

// ---------------- FFT helpers ----------------
template<int SGN>
__device__ __forceinline__ float2* fft512_r4(float2* bufA, float2* bufB, int tid){
  float2* src = bufA; float2* dst = bufB;
  #pragma unroll
  for (int st=0; st<4; st++){
    const int s = 1<<(2*st);
    const int n = 512>>(2*st);
    const int m = n>>2;
    if (tid < 128){
      int p = tid / s;
      int q = tid - p*s;
      float2 a0 = src[q + s*p];
      float2 a1 = src[q + s*(p+m)];
      float2 a2 = src[q + s*(p+2*m)];
      float2 a3 = src[q + s*(p+3*m)];
      float2 t0 = cadd(a0,a2), t1 = csub(a0,a2);
      float2 t2 = cadd(a1,a3), t3 = csub(a1,a3);
      float2 it3 = make_float2(-(float)SGN*t3.y, (float)SGN*t3.x);
      float2 r0 = cadd(t0,t2);
      float2 r1 = cadd(t1,it3);
      float2 r2 = csub(t0,t2);
      float2 r3 = csub(t1,it3);
      float ba = (float)SGN * ((float)(2.0*M_PI)/(float)n) * (float)p;
      dst[q + s*(4*p+0)] = r0;
      float sw,cw;
      __sincosf(ba, &sw, &cw);
      dst[q + s*(4*p+1)] = cmul(make_float2(cw,sw), r1);
      __sincosf(2.f*ba, &sw, &cw);
      dst[q + s*(4*p+2)] = cmul(make_float2(cw,sw), r2);
      __sincosf(3.f*ba, &sw, &cw);
      dst[q + s*(4*p+3)] = cmul(make_float2(cw,sw), r3);
    }
    __syncthreads();
    float2* tp = src; src = dst; dst = tp;
  }
  {
    float2 a = src[tid];
    float2 bb = src[tid+256];
    dst[tid]     = cadd(a,bb);
    dst[tid+256] = csub(a,bb);
    __syncthreads();
    float2* tp = src; src = dst; dst = tp;
  }
  return src;
}

__device__ __forceinline__ cplx w5k(int k, float sgn){
  const float C[5] = {1.f, 0.30901699f, -0.80901699f, -0.80901699f, 0.30901699f};
  const float S[5] = {0.f, 0.95105652f, 0.58778525f, -0.58778525f, -0.95105652f};
  return make_float2(C[k], sgn*S[k]);
}

template<int SGN>
__device__ __forceinline__ float2* fft125_rows(float2* bufA, float2* bufB, int tid){
  float2* src = bufA; float2* dst = bufB;
  #pragma unroll
  for (int st=0; st<3; st++){
    const int s = (st==0)?1:((st==1)?5:25);
    const int n = (st==0)?125:((st==1)?25:5);
    const int m = n/5;
    if (tid < 200){
      int row = tid/25, w = tid - row*25;
      int p = w/s, q = w - p*s;
      int base = row*125 + q;
      float2 a0 = src[base + s*p];
      float2 a1 = src[base + s*(p+m)];
      float2 a2 = src[base + s*(p+2*m)];
      float2 a3 = src[base + s*(p+3*m)];
      float2 a4 = src[base + s*(p+4*m)];
      #pragma unroll
      for (int r2=0;r2<5;r2++){
        float2 acc = a0;
        acc = cadd(acc, cmul(a1, w5k((1*r2)%5, (float)SGN)));
        acc = cadd(acc, cmul(a2, w5k((2*r2)%5, (float)SGN)));
        acc = cadd(acc, cmul(a3, w5k((3*r2)%5, (float)SGN)));
        acc = cadd(acc, cmul(a4, w5k((4*r2)%5, (float)SGN)));
        float ang = (float)SGN * ((float)(2.0*M_PI)/(float)n) * (float)(p*r2);
        float sw,cw; __sincosf(ang,&sw,&cw);
        dst[base + s*(5*p+r2)] = cmul(make_float2(cw,sw), acc);
      }
    }
    __syncthreads();
    float2* tp = src; src = dst; dst = tp;
  }
  return src;
}

__global__ __launch_bounds__(256) void k_fft512_fwd(){
  int p = blockIdx.x / 125, n1 = blockIdx.x % 125;
  int tid = threadIdx.x;
  __shared__ float2 bufA[512];
  __shared__ float2 bufB[512];
  const float* sa = g_signal + (size_t)(2*p)*T_;
  const float* sb = g_signal + (size_t)(2*p+1)*T_;
  for (int i=tid;i<512;i+=256) bufA[i] = make_float2(sa[n1 + 125*i], sb[n1 + 125*i]);
  __syncthreads();
  float2* res = fft512_r4<-1>(bufA, bufB, tid);
  for (int i=tid;i<512;i+=256){
    float ang = -(float)(2.0*M_PI/64000.0) * (float)(n1*i);
    float sw,cw; __sincosf(ang,&sw,&cw);
    g_W1[((size_t)p*512 + i)*125 + n1] = cmul(make_float2(cw,sw), res[i]);
  }
  if (blockIdx.x < B_){
    int b = blockIdx.x;
    double s1=0.0, s2=0.0;
    if (tid < 250){
      #pragma unroll
      for (int k=0;k<4;k++){
        int ch = tid*4 + k;
        s1 += g_part[(b*NCH+ch)*2];
        s2 += g_part[(b*NCH+ch)*2+1];
      }
    }
    for (int o=1;o<64;o<<=1){ s1 += __shfl_down(s1,o); s2 += __shfl_down(s2,o); }
    __shared__ double a1[4], a2[4];
    int lane = tid&63, wid = tid>>6;
    if (lane==0){ a1[wid]=s1; a2[wid]=s2; }
    __syncthreads();
    if (tid==0){
      double S1=a1[0]+a1[1]+a1[2]+a1[3], S2=a2[0]+a2[1]+a2[2]+a2[3];
      double mean = S1 / (double)T_;
      double var = (S2 - (double)T_*mean*mean) / (double)(T_-1);
      if (var < 0.0) var = 0.0;
      double rstd = 1.0/(sqrt(var) + 1e-8);
      g_stats[b*2] = mean; g_stats[b*2+1] = rstd;
    }
  }
}

__global__ __launch_bounds__(256) void k_fft125_mid(const float* __restrict__ ffq,
                                                    const float* __restrict__ fbw,
                                                    const float* __restrict__ fgn){
  int p = blockIdx.x / 64;
  int j = blockIdx.x % 64;
  int tid = threadIdx.x;
  __shared__ float2 bufA[1000];
  __shared__ float2 bufB[1000];
  int k2r[8];
  #pragma unroll
  for (int l=0;l<8;l++){
    int k2;
    if (l < 4) k2 = 4*j + l;
    else if (j==0 && l==4) k2 = 256;
    else k2 = 512 - 4*j - (l-4);
    k2r[l] = k2;
  }
  for (int i=tid;i<1000;i+=256){
    int l = i/125, n1 = i - l*125;
    bufA[i] = g_W1[((size_t)p*512 + k2r[l])*125 + n1];
  }
  float fca[4], bwa[4], ga[4], fcb[4], bwb[4], gb[4];
  int ba = 2*p, bb = 2*p+1;
  #pragma unroll
  for (int q=0;q<4;q++){
    size_t ia = ((size_t)ba*T_ + T_/2)*4 + q;
    size_t ib = ((size_t)bb*T_ + T_/2)*4 + q;
    fca[q]=ffq[ia]; bwa[q]=fbw[ia]; ga[q]=fgn[ia];
    fcb[q]=ffq[ib]; bwb[q]=fbw[ib]; gb[q]=fgn[ib];
  }
  __syncthreads();
  float2* X = fft125_rows<-1>(bufA, bufB, tid);
  float2* Y = (X == bufA) ? bufB : bufA;
  for (int i=tid;i<1000;i+=256){
    int l = i/125, k1 = i - l*125;
    int k2 = k2r[l];
    int lm = ((j==0) && (l==0 || l==4)) ? l : (l^4);
    int k1m = (k2 == 0) ? ((k1==0)?0:(125-k1)) : (124-k1);
    float2 Z1 = X[l*125 + k1];
    float2 Z2 = X[lm*125 + k1m];
    float xax = 0.5f*(Z1.x + Z2.x), xay = 0.5f*(Z1.y - Z2.y);
    float xbx = 0.5f*(Z1.y + Z2.y), xby = -0.5f*(Z1.x - Z2.x);
    int f = k2 + 512*k1;
    int fi = (f <= 32000) ? f : (64000 - f);
    float freq = (float)fi * 0.6890625f;
    float ra = 0.f, rb = 0.f;
    #pragma unroll
    for (int q=0;q<4;q++){
      float da = (freq - fca[q]) / (bwa[q]*0.5f);
      ra += ga[q] / (1.0f + da*da);
      float db = (freq - fcb[q]) / (bwb[q]*0.5f);
      rb += gb[q] / (1.0f + db*db);
    }
    float yax = ra*xax, yay = ra*xay;
    float ybx = rb*xbx, yby = rb*xby;
    Y[i] = make_float2(yax - yby, yay + ybx);
  }
  __syncthreads();
  float2* res2 = fft125_rows<1>(Y, X, tid);
  for (int i=tid;i<1000;i+=256){
    int l = i/125, n1 = i - l*125;
    int k2 = k2r[l];
    float ang = (float)(2.0*M_PI/64000.0) * (float)(n1*k2);
    float sw,cw; __sincosf(ang,&sw,&cw);
    g_Z[((size_t)p*125 + n1)*512 + k2] = cmul(make_float2(cw,sw), res2[i]);
  }
}

__global__ __launch_bounds__(256) void k_fft512_inv(const float* __restrict__ brth,
                                                    float* __restrict__ outp){
  int p = blockIdx.x / 125, n1 = blockIdx.x % 125;
  int tid = threadIdx.x;
  __shared__ float2 bufA[512];
  __shared__ float2 bufB[512];
  const float2* gin = g_Z + ((size_t)p*125 + n1)*512;
  for (int i=tid;i<512;i+=256) bufA[i] = gin[i];
  __syncthreads();
  float2* res = fft512_r4<1>(bufA, bufB, tid);
  int ba = 2*p, bb = 2*p+1;
  float mean_a = (float)g_stats[ba*2], rstd_a = (float)g_stats[ba*2+1];
  float mean_b = (float)g_stats[bb*2], rstd_b = (float)g_stats[bb*2+1];
  for (int i=tid;i<512;i+=256){
    int t = n1 + 125*i;
    float2 v = res[i];
    {
      int idx = ba*T_ + t;
      float filt = v.x * (1.0f/64000.0f);
      float br = brth[idx];
      float breath = (g_shaped[idx] - mean_a) * rstd_a;
      outp[idx] = filt*(1.0f - br) + breath*br;
    }
    {
      int idx = bb*T_ + t;
      float filt = v.y * (1.0f/64000.0f);
      float br = brth[idx];
      float breath = (g_shaped[idx] - mean_b) * rstd_b;
      outp[idx] = filt*(1.0f - br) + breath*br;
    }
  }
}

extern "C" void kernel_launch(void* const* d_in, const int* in_sizes, int n_in,
                              void* d_out, int out_size, void* d_ws, size_t ws_size,
                              hipStream_t stream){
  (void)in_sizes; (void)n_in; (void)out_size; (void)d_ws; (void)ws_size;
  const float* f0   = (const float*)d_in[0];
  const float* amps = (const float*)d_in[1];
  const float* vr   = (const float*)d_in[2];
  const float* vd   = (const float*)d_in[3];
  const float* ffq  = (const float*)d_in[4];
  const float* fbw  = (const float*)d_in[5];
  const float* fgn  = (const float*)d_in[6];
  const float* goq  = (const float*)d_in[7];
  const float* brth = (const float*)d_in[9];
  const float* bss  = (const float*)d_in[10];
  const float* iph  = (const float*)d_in[11];
  float* out = (float*)d_out;
  float* out_final = out + (size_t)B_*T_;

  k_phase<<<B_*250,256,0,stream>>>(bss, f0, vr, vd);
  k_sigbreath<<<B_*NCH,256,0,stream>>>(amps, goq, iph, out_final);
  k_fft512_fwd<<<250,256,0,stream>>>();
  k_fft125_mid<<<128,256,0,stream>>>(ffq, fbw, fgn);
  k_fft512_inv<<<250,256,0,stream>>>(brth, out);
}

// Round 20
// 55.969 us; speedup vs baseline: 1.1882x; 1.1882x over previous
//
#include <hip/hip_runtime.h>
#include <math.h>
#include <stdint.h>

#define B_ 4
#define T_ 64000
#define H_ 96
#define NCH 1000
#define TT_ 64
#define TWO_PI_D 6.283185307179586

typedef float2 cplx;
__device__ __forceinline__ cplx cadd(cplx a, cplx b){ return make_float2(a.x+b.x, a.y+b.y); }
__device__ __forceinline__ cplx csub(cplx a, cplx b){ return make_float2(a.x-b.x, a.y-b.y); }
__device__ __forceinline__ cplx cmul(cplx a, cplx b){ return make_float2(a.x*b.x - a.y*b.y, a.x*b.y + a.y*b.x); }

// ---------------- static scratch ----------------
__device__ float  g_dpf[B_*T_];
__device__ unsigned char g_hcnt[B_*T_];
__device__ float  g_signal[B_*T_];
__device__ float  g_shaped[B_*T_];
__device__ float  g_Kcomb[B_][132];
__device__ float2 g_W1[2*512*125];
__device__ float2 g_Z[2*125*512];
__device__ double g_chunksum[B_*NCH];
__device__ double g_stats[B_*2];
__device__ double g_part[B_*250*2];

// ---------------- fast f64 transcendentals ----------------
__device__ __forceinline__ double fsin64(double x){
  double z = x * 0.63661977236758138243;
  double fn = floor(z + 0.5);
  int k = (int)fn;
  const double p1 = 1.57079632673412561417e+00;
  const double p2 = 6.07710050650619224932e-11;
  double r = x - fn*p1;
  r = r - fn*p2;
  double s = r*r;
  double ps = 1.58969099521155010221e-10;
  ps = ps*s - 2.50507602534068634195e-08;
  ps = ps*s + 2.75573137070700676789e-06;
  ps = ps*s - 1.98412698298579493134e-04;
  ps = ps*s + 8.33333333332248946124e-03;
  ps = ps*s - 1.66666666666666324348e-01;
  double sr = r + r*s*ps;
  double pc = -1.13596475577881948265e-11;
  pc = pc*s + 2.08757232129817482790e-09;
  pc = pc*s - 2.75573143513906633035e-07;
  pc = pc*s + 2.48015872894767294178e-05;
  pc = pc*s - 1.38888888888741095749e-03;
  pc = pc*s + 4.16666666666666019037e-02;
  double cr = 1.0 - 0.5*s + s*s*pc;
  int m = k & 3;
  return (m==0) ? sr : (m==1) ? cr : (m==2) ? -sr : -cr;
}

__device__ __forceinline__ double fexp_small(double x){
  double p = 1.9841269841269841e-04;
  p = p*x + 1.3888888888888889e-03;
  p = p*x + 8.3333333333333332e-03;
  p = p*x + 4.1666666666666664e-02;
  p = p*x + 1.6666666666666666e-01;
  p = p*x + 0.5;
  p = p*x + 1.0;
  p = p*x + 1.0;
  return p;
}

// ---------------- threefry (partitionable, out0^out1) ----------------
__device__ __forceinline__ uint32_t rotl32(uint32_t x, int r){ return (x<<r)|(x>>(32-r)); }

__device__ __forceinline__ uint32_t threefry_bits(uint32_t i){
  uint32_t x0 = 0u, x1 = i;
  const uint32_t ks0 = 0u, ks1 = 42u, ks2 = 0u ^ 42u ^ 0x1BD11BDAu;
  x0 += ks0; x1 += ks1;
  #define TFR(r) { x0 += x1; x1 = rotl32(x1, r); x1 ^= x0; }
  TFR(13) TFR(15) TFR(26) TFR(6)   x0 += ks1; x1 += ks2 + 1u;
  TFR(17) TFR(29) TFR(16) TFR(24)  x0 += ks2; x1 += ks0 + 2u;
  TFR(13) TFR(15) TFR(26) TFR(6)   x0 += ks0; x1 += ks1 + 3u;
  TFR(17) TFR(29) TFR(16) TFR(24)  x0 += ks1; x1 += ks2 + 4u;
  TFR(13) TFR(15) TFR(26) TFR(6)   x0 += ks2; x1 += ks0 + 5u;
  #undef TFR
  return x0 ^ x1;
}

__device__ __forceinline__ float bits_to_normal(uint32_t bits){
  uint32_t mbits = (bits >> 9) | 0x3F800000u;
  float f = __uint_as_float(mbits) - 1.0f;
  const float lo = -0.99999994f;
  float x = f * 2.0f + lo;
  x = fmaxf(lo, x);
  float w = -log1pf(-x*x);
  float p;
  if (w < 5.0f){
    w -= 2.5f;
    p = 2.81022636e-08f;
    p = fmaf(p, w, 3.43273939e-07f);
    p = fmaf(p, w, -3.5233877e-06f);
    p = fmaf(p, w, -4.39150654e-06f);
    p = fmaf(p, w, 0.00021858087f);
    p = fmaf(p, w, -0.00125372503f);
    p = fmaf(p, w, -0.00417768164f);
    p = fmaf(p, w, 0.246640727f);
    p = fmaf(p, w, 1.50140941f);
  } else {
    w = sqrtf(w) - 3.0f;
    p = -0.000200214257f;
    p = fmaf(p, w, 0.000100950558f);
    p = fmaf(p, w, 0.00134934322f);
    p = fmaf(p, w, -0.00367342844f);
    p = fmaf(p, w, 0.00573950773f);
    p = fmaf(p, w, -0.0076224613f);
    p = fmaf(p, w, 0.00943887047f);
    p = fmaf(p, w, 1.00167406f);
    p = fmaf(p, w, 2.83297682f);
  }
  return 1.4142135623730951f * (p * x);
}

__constant__ int KSZc[8] = {129,91,65,45,33,23,17,11};

// ---------------- phase: increments + hcnt + chunksums (+ per-batch Kcomb in c==0) ----------------
__global__ __launch_bounds__(256) void k_phase(const float* __restrict__ bss,
                                               const float* __restrict__ f0,
                                               const float* __restrict__ vr,
                                               const float* __restrict__ vd){
  int b = blockIdx.x / 250, c = blockIdx.x % 250;
  int t0 = c*256, tid = threadIdx.x;
  if (c == 0){
    __shared__ float wn[8];
    {
      int i = tid >> 5, l32 = tid & 31;
      int ksz = KSZc[i];
      float sig = (float)ksz / 6.0f;
      float inv2s2 = 1.0f/(2.0f*sig*sig);
      int ctr = ksz>>1;
      float s = 0.f;
      for (int j = l32; j < ksz; j += 32){
        float d = (float)(j - ctr);
        s += expf(-d*d*inv2s2);
      }
      #pragma unroll
      for (int o=1;o<32;o<<=1) s += __shfl_xor(s, o);
      if (l32 == 0) wn[i] = bss[((size_t)b*T_ + T_/2)*8 + i] / s;
    }
    __syncthreads();
    if (tid < 129){
      int tau = tid - 64;
      float acc = 0.f;
      #pragma unroll
      for (int i=0;i<8;i++){
        int ksz = KSZc[i]; int hw = ksz>>1;
        if (tau >= -hw && tau <= hw){
          float sig = (float)ksz/6.0f;
          float inv2s2 = 1.0f/(2.0f*sig*sig);
          acc += expf(-(float)(tau*tau)*inv2s2) * wn[i];
        }
      }
      g_Kcomb[b][tid] = acc;
    }
  }
  int t = t0 + tid;
  int idx = b*T_ + t;
  double tt = (double)t * 2.2675736961451248e-05;      // 1/44100
  double argd = TWO_PI_D * (double)vr[idx] * tt;
  double argr = argd - TWO_PI_D * floor(argd * 0.15915494309189535);
  float svf = __sinf((float)argr);
  double lm = (double)vd[idx] * 0.057762265046662105;  // ln2/12
  double vm = fexp_small((double)svf * lm);
  double f0s = (double)f0[idx];
  double f0v = (f0s > 0.0) ? f0s * vm : f0s;
  int cnt;
  if (f0v <= 0.0) cnt = 96;
  else {
    int n = (int)(22050.0f / (float)f0v);
    if (!((double)n * f0v < 22050.0)) n--;
    if ((double)(n+1) * f0v < 22050.0) n++;
    double dlo = 22050.0 - (double)n * f0v;
    double dhi = (double)(n+1) * f0v - 22050.0;
    if (dlo < 0.01 || dhi < 0.01){
      double sv_d = fsin64(argd);
      double vm_d = fexp_small(sv_d * lm);
      double f0x = f0s * vm_d;
      int n2 = (int)(22050.0f / (float)f0x);
      if (!((double)n2 * f0x < 22050.0)) n2--;
      if ((double)(n2+1) * f0x < 22050.0) n2++;
      n = n2;
      f0v = f0x;
    }
    cnt = (n < 0) ? 0 : ((n > 96) ? 96 : n);
  }
  g_hcnt[idx] = (unsigned char)cnt;
  double v = f0v * 1.4247585730565955e-04;             // 2*pi/44100
  g_dpf[idx] = (float)v;
  int lane = tid & 63, wid = tid >> 6;
  for (int o=1;o<64;o<<=1) v += __shfl_down(v, o);
  if (lane == 0) g_chunksum[b*NCH + c*4 + wid] = v;
}

// ---------------- k_synth: heterogeneous blocks — signal (bid%5!=4) | breath (bid%5==4) ----------------
__global__ __launch_bounds__(256) void k_synth(const float* __restrict__ amps,
                                               const float* __restrict__ goq,
                                               const float* __restrict__ iph,
                                               float* __restrict__ out_final){
  __shared__ float sh_ns[384];
  __shared__ float sh_kl[132];
  __shared__ float sh_ph[TT_];
  __shared__ double sh_red[8];
  int bid = blockIdx.x;
  int tid = threadIdx.x;
  if ((bid % 5) == 4){
    // ===== breath block: 256 samples, serial 129-tap conv (no coupling to signal path) =====
    int bb = bid / 5;              // 0..999
    int b = bb / 250, c = bb % 250;
    int t0 = c * 256;
    for (int k = tid; k < 384; k += 256){
      int t = t0 - 64 + k;
      float nv = 0.f;
      if (t >= 0 && t < T_) nv = bits_to_normal(threefry_bits((uint32_t)(b*T_ + t)));
      sh_ns[k] = nv;
    }
    for (int k = tid; k < 129; k += 256) sh_kl[k] = g_Kcomb[b][k];
    __syncthreads();
    float acc = 0.f;
    for (int j = 0; j < 129; j++) acc = fmaf(sh_ns[tid + j], sh_kl[j], acc);
    g_shaped[b*T_ + t0 + tid] = acc;
    double xx = (double)acc;
    double s1 = xx, s2 = xx*xx;
    for (int o=1;o<64;o<<=1){ s1 += __shfl_down(s1,o); s2 += __shfl_down(s2,o); }
    int lane = tid&63, wid = tid>>6;
    if (lane==0){ sh_red[wid] = s1; sh_red[4+wid] = s2; }
    __syncthreads();
    if (tid==0){
      g_part[(b*250+c)*2]   = sh_red[0]+sh_red[1]+sh_red[2]+sh_red[3];
      g_part[(b*250+c)*2+1] = sh_red[4]+sh_red[5]+sh_red[6]+sh_red[7];
    }
  } else {
    // ===== signal block: 64 samples × 4 threads (r18 form: preissued direct loads) =====
    int sb = bid - bid/5;          // 0..3999
    int b = sb / NCH, c = sb % NCH;
    int t0 = c * TT_;
    int tl = tid >> 2, part = tid & 3;
    const float4* Ar = (const float4*)(amps + ((size_t)b*T_ + t0 + tl)*H_ + part*24);
    float4 a0 = Ar[0], a1 = Ar[1], a2 = Ar[2], a3 = Ar[3], a4 = Ar[4], a5 = Ar[5];
    int idx = b*T_ + t0 + tl;
    int hc = (int)g_hcnt[idx];
    float oq = goq[idx];
    if (tid < 64){
      double s = 0.0;
      for (int ch = tid; ch < c; ch += 64) s += g_chunksum[b*NCH + ch];
      for (int o=1;o<64;o<<=1) s += __shfl_xor(s, o);
      double base = s + (double)iph[b];
      int idq = b*T_ + t0 + tid;
      double v = (double)g_dpf[idq];
      for (int o=1;o<64;o<<=1){ double u = __shfl_up(v, o); if (tid >= o) v += u; }
      sh_ph[tid] = (float)fmod(base + v, TWO_PI_D);
      if (c == NCH-1 && tid == 63) out_final[b] = (float)fmod(base + v, TWO_PI_D);
    }
    __syncthreads();
    float r = sh_ph[tl];
    float k1 = 3.14159265358979f / oq;
    float k2 = 3.14159265358979f / (1.0f - oq);
    float offA = 3.14159265358979f;
    float offB = -oq * k2;
    float r0 = r * 0.15915494309189535f;
    int hbase = part*24;
    float sum = 0.f;
    float av[24] = {a0.x,a0.y,a0.z,a0.w, a1.x,a1.y,a1.z,a1.w, a2.x,a2.y,a2.z,a2.w,
                    a3.x,a3.y,a3.z,a3.w, a4.x,a4.y,a4.z,a4.w, a5.x,a5.y,a5.z,a5.w};
    #pragma unroll
    for (int e=0;e<24;e++){
      int h = hbase + e;
      float amp = (h < hc) ? av[e] : 0.0f;
      float nn = (float)(h+1);
      float fr = nn * r0;
      fr = fr - floorf(fr);
      bool ris = fr < oq;
      float kk  = ris ? k1 : k2;
      float off = ris ? offA : offB;
      float cv = __cosf(fmaf(fr, kk, off));
      sum = fmaf(cv, amp, sum);
    }
    sum += __shfl_xor(sum, 1);
    sum += __shfl_xor(sum, 2);
    if (part == 0) g_signal[idx] = 0.5f * sum;
  }
}

// ---------------- FFT helpers ----------------
template<int SGN>
__device__ __forceinline__ float2* fft512_r4(float2* bufA, float2* bufB, int tid){
  float2* src = bufA; float2* dst = bufB;
  #pragma unroll
  for (int st=0; st<4; st++){
    const int s = 1<<(2*st);
    const int n = 512>>(2*st);
    const int m = n>>2;
    if (tid < 128){
      int p = tid / s;
      int q = tid - p*s;
      float2 a0 = src[q + s*p];
      float2 a1 = src[q + s*(p+m)];
      float2 a2 = src[q + s*(p+2*m)];
      float2 a3 = src[q + s*(p+3*m)];
      float2 t0 = cadd(a0,a2), t1 = csub(a0,a2);
      float2 t2 = cadd(a1,a3), t3 = csub(a1,a3);
      float2 it3 = make_float2(-(float)SGN*t3.y, (float)SGN*t3.x);
      float2 r0 = cadd(t0,t2);
      float2 r1 = cadd(t1,it3);
      float2 r2 = csub(t0,t2);
      float2 r3 = csub(t1,it3);
      float ba = (float)SGN * ((float)(2.0*M_PI)/(float)n) * (float)p;
      dst[q + s*(4*p+0)] = r0;
      float sw,cw;
      __sincosf(ba, &sw, &cw);
      dst[q + s*(4*p+1)] = cmul(make_float2(cw,sw), r1);
      __sincosf(2.f*ba, &sw, &cw);
      dst[q + s*(4*p+2)] = cmul(make_float2(cw,sw), r2);
      __sincosf(3.f*ba, &sw, &cw);
      dst[q + s*(4*p+3)] = cmul(make_float2(cw,sw), r3);
    }
    __syncthreads();
    float2* tp = src; src = dst; dst = tp;
  }
  {
    float2 a = src[tid];
    float2 bb = src[tid+256];
    dst[tid]     = cadd(a,bb);
    dst[tid+256] = csub(a,bb);
    __syncthreads();
    float2* tp = src; src = dst; dst = tp;
  }
  return src;
}

__device__ __forceinline__ cplx w5k(int k, float sgn){
  const float C[5] = {1.f, 0.30901699f, -0.80901699f, -0.80901699f, 0.30901699f};
  const float S[5] = {0.f, 0.95105652f, 0.58778525f, -0.58778525f, -0.95105652f};
  return make_float2(C[k], sgn*S[k]);
}

template<int SGN>
__device__ __forceinline__ float2* fft125_rows(float2* bufA, float2* bufB, int tid){
  float2* src = bufA; float2* dst = bufB;
  #pragma unroll
  for (int st=0; st<3; st++){
    const int s = (st==0)?1:((st==1)?5:25);
    const int n = (st==0)?125:((st==1)?25:5);
    const int m = n/5;
    if (tid < 200){
      int row = tid/25, w = tid - row*25;
      int p = w/s, q = w - p*s;
      int base = row*125 + q;
      float2 a0 = src[base + s*p];
      float2 a1 = src[base + s*(p+m)];
      float2 a2 = src[base + s*(p+2*m)];
      float2 a3 = src[base + s*(p+3*m)];
      float2 a4 = src[base + s*(p+4*m)];
      #pragma unroll
      for (int r2=0;r2<5;r2++){
        float2 acc = a0;
        acc = cadd(acc, cmul(a1, w5k((1*r2)%5, (float)SGN)));
        acc = cadd(acc, cmul(a2, w5k((2*r2)%5, (float)SGN)));
        acc = cadd(acc, cmul(a3, w5k((3*r2)%5, (float)SGN)));
        acc = cadd(acc, cmul(a4, w5k((4*r2)%5, (float)SGN)));
        float ang = (float)SGN * ((float)(2.0*M_PI)/(float)n) * (float)(p*r2);
        float sw,cw; __sincosf(ang,&sw,&cw);
        dst[base + s*(5*p+r2)] = cmul(make_float2(cw,sw), acc);
      }
    }
    __syncthreads();
    float2* tp = src; src = dst; dst = tp;
  }
  return src;
}

__global__ __launch_bounds__(256) void k_fft512_fwd(){
  int p = blockIdx.x / 125, n1 = blockIdx.x % 125;
  int tid = threadIdx.x;
  __shared__ float2 bufA[512];
  __shared__ float2 bufB[512];
  const float* sa = g_signal + (size_t)(2*p)*T_;
  const float* sb = g_signal + (size_t)(2*p+1)*T_;
  for (int i=tid;i<512;i+=256) bufA[i] = make_float2(sa[n1 + 125*i], sb[n1 + 125*i]);
  __syncthreads();
  float2* res = fft512_r4<-1>(bufA, bufB, tid);
  for (int i=tid;i<512;i+=256){
    float ang = -(float)(2.0*M_PI/64000.0) * (float)(n1*i);
    float sw,cw; __sincosf(ang,&sw,&cw);
    g_W1[((size_t)p*512 + i)*125 + n1] = cmul(make_float2(cw,sw), res[i]);
  }
  if (blockIdx.x < B_){
    int b = blockIdx.x;
    double s1=0.0, s2=0.0;
    if (tid < 250){ s1 = g_part[(b*250+tid)*2]; s2 = g_part[(b*250+tid)*2+1]; }
    for (int o=1;o<64;o<<=1){ s1 += __shfl_down(s1,o); s2 += __shfl_down(s2,o); }
    __shared__ double a1[4], a2[4];
    int lane = tid&63, wid = tid>>6;
    if (lane==0){ a1[wid]=s1; a2[wid]=s2; }
    __syncthreads();
    if (tid==0){
      double S1=a1[0]+a1[1]+a1[2]+a1[3], S2=a2[0]+a2[1]+a2[2]+a2[3];
      double mean = S1 / (double)T_;
      double var = (S2 - (double)T_*mean*mean) / (double)(T_-1);
      if (var < 0.0) var = 0.0;
      double rstd = 1.0/(sqrt(var) + 1e-8);
      g_stats[b*2] = mean; g_stats[b*2+1] = rstd;
    }
  }
}

__global__ __launch_bounds__(256) void k_fft125_mid(const float* __restrict__ ffq,
                                                    const float* __restrict__ fbw,
                                                    const float* __restrict__ fgn){
  int p = blockIdx.x / 64;
  int j = blockIdx.x % 64;
  int tid = threadIdx.x;
  __shared__ float2 bufA[1000];
  __shared__ float2 bufB[1000];
  int k2r[8];
  #pragma unroll
  for (int l=0;l<8;l++){
    int k2;
    if (l < 4) k2 = 4*j + l;
    else if (j==0 && l==4) k2 = 256;
    else k2 = 512 - 4*j - (l-4);
    k2r[l] = k2;
  }
  for (int i=tid;i<1000;i+=256){
    int l = i/125, n1 = i - l*125;
    bufA[i] = g_W1[((size_t)p*512 + k2r[l])*125 + n1];
  }
  float fca[4], bwa[4], ga[4], fcb[4], bwb[4], gb[4];
  int ba = 2*p, bb = 2*p+1;
  #pragma unroll
  for (int q=0;q<4;q++){
    size_t ia = ((size_t)ba*T_ + T_/2)*4 + q;
    size_t ib = ((size_t)bb*T_ + T_/2)*4 + q;
    fca[q]=ffq[ia]; bwa[q]=fbw[ia]; ga[q]=fgn[ia];
    fcb[q]=ffq[ib]; bwb[q]=fbw[ib]; gb[q]=fgn[ib];
  }
  __syncthreads();
  float2* X = fft125_rows<-1>(bufA, bufB, tid);
  float2* Y = (X == bufA) ? bufB : bufA;
  for (int i=tid;i<1000;i+=256){
    int l = i/125, k1 = i - l*125;
    int k2 = k2r[l];
    int lm = ((j==0) && (l==0 || l==4)) ? l : (l^4);
    int k1m = (k2 == 0) ? ((k1==0)?0:(125-k1)) : (124-k1);
    float2 Z1 = X[l*125 + k1];
    float2 Z2 = X[lm*125 + k1m];
    float xax = 0.5f*(Z1.x + Z2.x), xay = 0.5f*(Z1.y - Z2.y);
    float xbx = 0.5f*(Z1.y + Z2.y), xby = -0.5f*(Z1.x - Z2.x);
    int f = k2 + 512*k1;
    int fi = (f <= 32000) ? f : (64000 - f);
    float freq = (float)fi * 0.6890625f;
    float ra = 0.f, rb = 0.f;
    #pragma unroll
    for (int q=0;q<4;q++){
      float da = (freq - fca[q]) / (bwa[q]*0.5f);
      ra += ga[q] / (1.0f + da*da);
      float db = (freq - fcb[q]) / (bwb[q]*0.5f);
      rb += gb[q] / (1.0f + db*db);
    }
    float yax = ra*xax, yay = ra*xay;
    float ybx = rb*xbx, yby = rb*xby;
    Y[i] = make_float2(yax - yby, yay + ybx);
  }
  __syncthreads();
  float2* res2 = fft125_rows<1>(Y, X, tid);
  for (int i=tid;i<1000;i+=256){
    int l = i/125, n1 = i - l*125;
    int k2 = k2r[l];
    float ang = (float)(2.0*M_PI/64000.0) * (float)(n1*k2);
    float sw,cw; __sincosf(ang,&sw,&cw);
    g_Z[((size_t)p*125 + n1)*512 + k2] = cmul(make_float2(cw,sw), res2[i]);
  }
}

__global__ __launch_bounds__(256) void k_fft512_inv(const float* __restrict__ brth,
                                                    float* __restrict__ outp){
  int p = blockIdx.x / 125, n1 = blockIdx.x % 125;
  int tid = threadIdx.x;
  __shared__ float2 bufA[512];
  __shared__ float2 bufB[512];
  const float2* gin = g_Z + ((size_t)p*125 + n1)*512;
  for (int i=tid;i<512;i+=256) bufA[i] = gin[i];
  __syncthreads();
  float2* res = fft512_r4<1>(bufA, bufB, tid);
  int ba = 2*p, bb = 2*p+1;
  float mean_a = (float)g_stats[ba*2], rstd_a = (float)g_stats[ba*2+1];
  float mean_b = (float)g_stats[bb*2], rstd_b = (float)g_stats[bb*2+1];
  for (int i=tid;i<512;i+=256){
    int t = n1 + 125*i;
    float2 v = res[i];
    {
      int idx = ba*T_ + t;
      float filt = v.x * (1.0f/64000.0f);
      float br = brth[idx];
      float breath = (g_shaped[idx] - mean_a) * rstd_a;
      outp[idx] = filt*(1.0f - br) + breath*br;
    }
    {
      int idx = bb*T_ + t;
      float filt = v.y * (1.0f/64000.0f);
      float br = brth[idx];
      float breath = (g_shaped[idx] - mean_b) * rstd_b;
      outp[idx] = filt*(1.0f - br) + breath*br;
    }
  }
}

extern "C" void kernel_launch(void* const* d_in, const int* in_sizes, int n_in,
                              void* d_out, int out_size, void* d_ws, size_t ws_size,
                              hipStream_t stream){
  (void)in_sizes; (void)n_in; (void)out_size; (void)d_ws; (void)ws_size;
  const float* f0   = (const float*)d_in[0];
  const float* amps = (const float*)d_in[1];
  const float* vr   = (const float*)d_in[2];
  const float* vd   = (const float*)d_in[3];
  const float* ffq  = (const float*)d_in[4];
  const float* fbw  = (const float*)d_in[5];
  const float* fgn  = (const float*)d_in[6];
  const float* goq  = (const float*)d_in[7];
  const float* brth = (const float*)d_in[9];
  const float* bss  = (const float*)d_in[10];
  const float* iph  = (const float*)d_in[11];
  float* out = (float*)d_out;
  float* out_final = out + (size_t)B_*T_;

  k_phase<<<B_*250,256,0,stream>>>(bss, f0, vr, vd);
  k_synth<<<5000,256,0,stream>>>(amps, goq, iph, out_final);
  k_fft512_fwd<<<250,256,0,stream>>>();
  k_fft125_mid<<<128,256,0,stream>>>(ffq, fbw, fgn);
  k_fft512_inv<<<250,256,0,stream>>>(brth, out);
}